// Round 2
// baseline (3953.453 us; speedup 1.0000x reference)
//
#include <hip/hip_runtime.h>
#include <stdint.h>

#define ROT(x, r) __builtin_rotateleft32((uint32_t)(x), (r))

#define TF_G1(x0, x1) \
  x0 += x1; x1 = ROT(x1, 13); x1 ^= x0; \
  x0 += x1; x1 = ROT(x1, 15); x1 ^= x0; \
  x0 += x1; x1 = ROT(x1, 26); x1 ^= x0; \
  x0 += x1; x1 = ROT(x1, 6);  x1 ^= x0;

#define TF_G2(x0, x1) \
  x0 += x1; x1 = ROT(x1, 17); x1 ^= x0; \
  x0 += x1; x1 = ROT(x1, 29); x1 ^= x0; \
  x0 += x1; x1 = ROT(x1, 16); x1 ^= x0; \
  x0 += x1; x1 = ROT(x1, 24); x1 ^= x0;

__device__ __forceinline__ void threefry_full(uint32_t k0, uint32_t k1,
                                              uint32_t c0, uint32_t c1,
                                              uint32_t& o0, uint32_t& o1) {
  uint32_t ks2 = k0 ^ k1 ^ 0x1BD11BDAu;
  uint32_t x0 = c0 + k0, x1 = c1 + k1;
  TF_G1(x0, x1); x0 += k1;  x1 += ks2 + 1u;
  TF_G2(x0, x1); x0 += ks2; x1 += k0 + 2u;
  TF_G1(x0, x1); x0 += k0;  x1 += k1 + 3u;
  TF_G2(x0, x1); x0 += k1;  x1 += ks2 + 4u;
  TF_G1(x0, x1); x0 += ks2; x1 += k0 + 5u;
  o0 = x0; o1 = x1;
}

// partitionable-mode draw: counts=(0,cnt), bits = out0 ^ out1
__device__ __forceinline__ uint32_t tf_bits(uint32_t k0, uint32_t k1, uint32_t ks2,
                                            uint32_t cnt) {
  uint32_t x0 = k0;
  uint32_t x1 = cnt + k1;
  TF_G1(x0, x1); x0 += k1;  x1 += ks2 + 1u;
  TF_G2(x0, x1); x0 += ks2; x1 += k0 + 2u;
  TF_G1(x0, x1); x0 += k0;  x1 += k1 + 3u;
  TF_G2(x0, x1); x0 += k1;  x1 += ks2 + 4u;
  TF_G1(x0, x1); x0 += ks2; x1 += k0 + 5u;
  return x0 ^ x1;
}

#define R 16      // rows per block
#define TT 16     // timesteps per tile (last tile uses 4)
#define NJW 25    // 784 bits -> 25 u32 words (top 16 bits of word 24 are pad)
#define XN 12845056u  // 16384*784

// WT[j][o] padded to [800][16], zeros outside [784][10]
__global__ void prep_wt(const float* __restrict__ W, float* __restrict__ wt) {
  int i = blockIdx.x * 256 + threadIdx.x;
  if (i >= 800 * 16) return;
  int j = i >> 4, o = i & 15;
  wt[i] = (j < 784 && o < 10) ? W[o * 784 + j] : 0.0f;
}

__global__ __launch_bounds__(256, 4)
void snn_kernel(const float* __restrict__ x, const float* __restrict__ wt,
                float* __restrict__ out) {
  __shared__ uint32_t keys[100][2];
  __shared__ uint32_t masks[R * TT][NJW];   // [pair][jj], pair = row*Ta + t
  __shared__ float Ild[TT][R][12];          // [t][row][o], o padded to 12

  const int tid = threadIdx.x;
  const int lane = tid & 63;
  const int w = tid >> 6;
  const int hl = lane & 31;
  const int half = lane >> 5;
  const int row0 = blockIdx.x * R;

  if (tid < 100) {
    threefry_full(0u, 42u, 0u, (uint32_t)tid, keys[tid][0], keys[tid][1]);
  }

  // LIF state: lanes tid<160 own (row=tid/10, o=tid%10)
  float v = 0.0f, acc = 0.0f;
  const int p3row = tid / 10;
  const int p3o = tid - p3row * 10;

  __syncthreads();

  for (int t0 = 0; t0 < 100; t0 += TT) {
    const int Ta = (100 - t0 >= TT) ? TT : (100 - t0);   // 16 or 4
    const int shift = (Ta == 16) ? 4 : 2;
    const int niter = (R * Ta) >> 3;                     // 8 pairs per block-iter

    // ---- phase 1: spike generation, ballot-packed into LDS masks ----
    for (int it = 0; it < niter; ++it) {
      const int pair = it * 8 + w * 2 + half;   // both halves share row (t even/odd)
      const int row = pair >> shift;
      const int t = pair & (Ta - 1);
      const uint32_t k0 = keys[t0 + t][0];
      const uint32_t k1 = keys[t0 + t][1];
      const uint32_t ks2 = k0 ^ k1 ^ 0x1BD11BDAu;
      const uint32_t cntb = (uint32_t)(row0 + row) * 784u + (uint32_t)hl;
#pragma unroll 5
      for (int jj = 0; jj < NJW; ++jj) {
        const uint32_t cnt = cntb + 32u * (uint32_t)jj;
        uint32_t xin = (cnt < XN) ? cnt : (XN - 1u);
        const float xv = x[xin];
        uint32_t xi9 = ((uint32_t)(xv * 8388608.0f)) << 9;  // exact: x = k*2^-23
        if ((jj << 5) + hl >= 784) xi9 = 0u;                // pad lanes never spike
        const uint32_t bits = tf_bits(k0, k1, ks2, cnt);
        const unsigned long long m = __ballot(bits < xi9);  // u<x bit-exact
        if (hl == 0)
          masks[pair][jj] = (half == 0) ? (uint32_t)m : (uint32_t)(m >> 32);
      }
    }
    __syncthreads();

    // ---- phase 2: binary GEMV, lane = (row, t), scalar weights ----
    {
      const int row = tid >> 4;
      const int t = tid & 15;
      if (t < Ta) {
        const int pair = row * Ta + t;
        float I[10];
#pragma unroll
        for (int o = 0; o < 10; ++o) I[o] = 0.0f;
        for (int jj = 0; jj < NJW; ++jj) {
          const uint32_t m = masks[pair][jj];
          const float* wbase = wt + (jj << 5) * 16;
#pragma unroll
          for (int b = 0; b < 32; ++b) {
            const float s = (float)((m >> b) & 1u);
            const float* wrow = wbase + b * 16;   // wave-uniform -> s_load
#pragma unroll
            for (int o = 0; o < 10; ++o) I[o] += s * wrow[o];
          }
        }
        float4* dst = (float4*)&Ild[t][row][0];
        dst[0] = make_float4(I[0], I[1], I[2], I[3]);
        dst[1] = make_float4(I[4], I[5], I[6], I[7]);
        Ild[t][row][8] = I[8];
        Ild[t][row][9] = I[9];
      }
    }
    __syncthreads();

    // ---- phase 3: LIF scan over this tile's timesteps ----
    if (tid < R * 10) {
#pragma unroll 4
      for (int t = 0; t < Ta; ++t) {
        const float I = Ild[t][p3row][p3o];
        const float vv = v + (I - v) * 0.5f;          // v += (I - v)/tau, exact
        const float s = (vv >= 1.0f) ? 1.0f : 0.0f;   // spike
        acc += s;
        v = (1.0f - s) * vv;                          // hard reset
      }
    }
    __syncthreads();
  }

  if (tid < R * 10) {
    out[(size_t)(row0 + p3row) * 10 + p3o] = acc / 100.0f;
  }
}

extern "C" void kernel_launch(void* const* d_in, const int* in_sizes, int n_in,
                              void* d_out, int out_size, void* d_ws, size_t ws_size,
                              hipStream_t stream) {
  const float* x = (const float*)d_in[0];   // [16384,1,28,28] fp32
  const float* W = (const float*)d_in[1];   // [10,784] fp32
  float* out = (float*)d_out;               // [16384,10] fp32
  float* wt = (float*)d_ws;                 // [800][16] padded W^T, 51.2 KB

  hipLaunchKernelGGL(prep_wt, dim3((800 * 16 + 255) / 256), dim3(256), 0, stream, W, wt);
  hipLaunchKernelGGL(snn_kernel, dim3(16384 / R), dim3(256), 0, stream, x, wt, out);
}